// Round 15
// baseline (300.653 us; speedup 1.0000x reference)
//
#include <hip/hip_runtime.h>
#include <hip/hip_bf16.h>
#include <math.h>

typedef __bf16 bf16x8 __attribute__((ext_vector_type(8)));
typedef float f32x4 __attribute__((ext_vector_type(4)));
typedef unsigned short u16x8 __attribute__((ext_vector_type(8)));

#define DEV __device__ __forceinline__

DEV unsigned short f2bf(float f){ __hip_bfloat16 h=__float2bfloat16(f); unsigned short u; __builtin_memcpy(&u,&h,2); return u; }
DEV float bf2f(unsigned short u){ __hip_bfloat16 h; __builtin_memcpy(&h,&u,2); return __bfloat162float(h); }

// tanh-form GELU: exp is HW (v_exp_f32), rcp is HW.
DEV float gelu_f(float v){
  float u = v*(0.7978845608f + 0.0356774081f*v*v);
  float e = __expf(2.0f*u);
  float t = 1.0f - 2.0f*__builtin_amdgcn_rcpf(e + 1.0f);
  return 0.5f*v*(1.0f + t);
}

DEV void gl2lds16(const void* g, void* l){
  __builtin_amdgcn_global_load_lds((const __attribute__((address_space(1))) void*)g,
                                   (__attribute__((address_space(3))) void*)l, 16, 0, 0);
}

// ---- tiled weight transpose: WT[n][k] (bf16) = W[k][n] (f32), 64x64 tiles.
__global__ __launch_bounds__(256) void k_wtt(const float* __restrict__ w1a,
                                             const float* __restrict__ w1b,
                                             const float* __restrict__ w2a,
                                             const float* __restrict__ w2b,
                                             unsigned short* __restrict__ o1a,
                                             unsigned short* __restrict__ o1b,
                                             unsigned short* __restrict__ o2a,
                                             unsigned short* __restrict__ o2b){
  __shared__ float tl[64][65];
  int bid = blockIdx.x;
  const float* W; unsigned short* O; int NN, tile_id;
  if (bid < 16)      { W = w1a; O = o1a; NN = 256; tile_id = bid; }
  else if (bid < 32) { W = w1b; O = o1b; NN = 256; tile_id = bid - 16; }
  else if (bid < 96) { W = w2a; O = o2a; NN = 512; tile_id = bid - 32; }
  else               { W = w2b; O = o2b; NN = 512; tile_id = bid - 96; }
  int tpr = NN >> 6;
  int tr = tile_id / tpr, tc = tile_id % tpr;
  int tid = threadIdx.x;
  int r = tid >> 2, cseg = (tid & 3) << 4;
  #pragma unroll
  for (int j = 0; j < 4; ++j){
    float4 v = *(const float4*)(W + (size_t)(tr*64 + r)*NN + tc*64 + cseg + j*4);
    tl[r][cseg + j*4 + 0] = v.x;
    tl[r][cseg + j*4 + 1] = v.y;
    tl[r][cseg + j*4 + 2] = v.z;
    tl[r][cseg + j*4 + 3] = v.w;
  }
  __syncthreads();
  int rn = tid >> 2, kseg = (tid & 3) << 4;
  #pragma unroll
  for (int h = 0; h < 2; ++h){
    u16x8 o;
    #pragma unroll
    for (int j = 0; j < 8; ++j) o[j] = f2bf(tl[kseg + h*8 + j][rn]);
    *(u16x8*)(O + (size_t)(tc*64 + rn)*NN + tr*64 + kseg + h*8) = o;
  }
}

// ---- LN1 + transpose: x[b][p][c] f32 -> ht[b][c][p] bf16 (layernormed)
__global__ __launch_bounds__(512) void k_ln1x(const float* __restrict__ x,
                                              const float* __restrict__ g,
                                              const float* __restrict__ be,
                                              unsigned short* __restrict__ ht){
  __shared__ unsigned short tile[32][512];
  int blk = blockIdx.x;
  int b = blk >> 3, p0 = (blk & 7) << 5;
  int tid = threadIdx.x, w = tid >> 6, l = tid & 63;
  float4 gv0 = *(const float4*)(g  + l*8);
  float4 gv1 = *(const float4*)(g  + l*8 + 4);
  float4 bv0 = *(const float4*)(be + l*8);
  float4 bv1 = *(const float4*)(be + l*8 + 4);
  const float* xbase = x + (((size_t)b << 8) + p0) * 512;
  #pragma unroll
  for (int i = 0; i < 4; ++i){
    int pl = (i << 3) + w;
    const float* row = xbase + (size_t)pl*512 + l*8;
    float4 v0 = *(const float4*)row;
    float4 v1 = *(const float4*)(row + 4);
    float s  = v0.x+v0.y+v0.z+v0.w + v1.x+v1.y+v1.z+v1.w;
    float s2 = v0.x*v0.x+v0.y*v0.y+v0.z*v0.z+v0.w*v0.w
             + v1.x*v1.x+v1.y*v1.y+v1.z*v1.z+v1.w*v1.w;
    #pragma unroll
    for (int off = 32; off; off >>= 1){ s += __shfl_xor(s, off); s2 += __shfl_xor(s2, off); }
    float mu = s * (1.0f/512.0f);
    float rs = rsqrtf(s2*(1.0f/512.0f) - mu*mu + 1e-6f);
    u16x8 o;
    o[0]=f2bf((v0.x-mu)*rs*gv0.x+bv0.x);
    o[1]=f2bf((v0.y-mu)*rs*gv0.y+bv0.y);
    o[2]=f2bf((v0.z-mu)*rs*gv0.z+bv0.z);
    o[3]=f2bf((v0.w-mu)*rs*gv0.w+bv0.w);
    o[4]=f2bf((v1.x-mu)*rs*gv1.x+bv1.x);
    o[5]=f2bf((v1.y-mu)*rs*gv1.y+bv1.y);
    o[6]=f2bf((v1.z-mu)*rs*gv1.z+bv1.z);
    o[7]=f2bf((v1.w-mu)*rs*gv1.w+bv1.w);
    *(u16x8*)(&tile[pl][(l ^ ((pl >> 3) << 1)) << 3]) = o;   // swizzled chunk
  }
  __syncthreads();
  unsigned short* hb = ht + ((size_t)b << 17);   // b * 512 * 256
  #pragma unroll
  for (int it = 0; it < 4; ++it){
    int c = (it << 7) + (tid >> 2);
    int q = tid & 3, pch = q << 3;
    int cs = c ^ (q << 4);
    u16x8 o;
    #pragma unroll
    for (int j = 0; j < 8; ++j) o[j] = tile[pch + j][cs];
    *(u16x8*)(hb + (size_t)c*256 + p0 + pch) = o;
  }
}

// ---- streaming residual + LN2, one row per wave; residual read from x (f32):
// h2[r][c] = LN( t[r][c] + x[r][c] ),  r = (b,p)
__global__ __launch_bounds__(256) void k_tl2s(const unsigned short* __restrict__ t,
                                              const float* __restrict__ x,
                                              const float* __restrict__ g,
                                              const float* __restrict__ be,
                                              unsigned short* __restrict__ h2){
  int tid = threadIdx.x, w = tid >> 6, l = tid & 63;
  float4 gv0 = *(const float4*)(g  + l*8);
  float4 gv1 = *(const float4*)(g  + l*8 + 4);
  float4 bv0 = *(const float4*)(be + l*8);
  float4 bv1 = *(const float4*)(be + l*8 + 4);
  int r = blockIdx.x*4 + w;
  size_t off = (size_t)r*512 + l*8;
  u16x8 tv = *(const u16x8*)(t + off);
  float4 x0 = *(const float4*)(x + off);
  float4 x1 = *(const float4*)(x + off + 4);
  float v[8];
  v[0] = bf2f(tv[0]) + x0.x;
  v[1] = bf2f(tv[1]) + x0.y;
  v[2] = bf2f(tv[2]) + x0.z;
  v[3] = bf2f(tv[3]) + x0.w;
  v[4] = bf2f(tv[4]) + x1.x;
  v[5] = bf2f(tv[5]) + x1.y;
  v[6] = bf2f(tv[6]) + x1.z;
  v[7] = bf2f(tv[7]) + x1.w;
  float s = 0.f, s2 = 0.f;
  #pragma unroll
  for (int j = 0; j < 8; ++j){ s += v[j]; s2 += v[j]*v[j]; }
  #pragma unroll
  for (int o2i = 32; o2i; o2i >>= 1){ s += __shfl_xor(s, o2i); s2 += __shfl_xor(s2, o2i); }
  float mu = s * (1.0f/512.0f);
  float rs = rsqrtf(s2*(1.0f/512.0f) - mu*mu + 1e-6f);
  u16x8 o;
  o[0]=f2bf((v[0]-mu)*rs*gv0.x+bv0.x);
  o[1]=f2bf((v[1]-mu)*rs*gv0.y+bv0.y);
  o[2]=f2bf((v[2]-mu)*rs*gv0.z+bv0.z);
  o[3]=f2bf((v[3]-mu)*rs*gv0.w+bv0.w);
  o[4]=f2bf((v[4]-mu)*rs*gv1.x+bv1.x);
  o[5]=f2bf((v[5]-mu)*rs*gv1.y+bv1.y);
  o[6]=f2bf((v[6]-mu)*rs*gv1.z+bv1.z);
  o[7]=f2bf((v[7]-mu)*rs*gv1.w+bv1.w);
  *(u16x8*)(h2 + off) = o;
}

// ---- fused token MLP:
// t[b][p][c] = b1b[p] + sum_p1 wt1b[p][p1] * gelu(b1a[p1] + sum_p' ht[bc][p']*wt1a[p1][p'])
__global__ __launch_bounds__(256, 2) void k_tok(
    const unsigned short* __restrict__ ht,    // [131072][256]
    const unsigned short* __restrict__ w1aT,  // [p1][p'] 256x256
    const unsigned short* __restrict__ w1bT,  // [p][p1]  256x256
    const float* __restrict__ b1a,
    const float* __restrict__ b1b,
    unsigned short* __restrict__ t)           // [256][256][512]
{
  constexpr int EPITCH = 144;                 // 16B-aligned epilogue pitch
  __shared__ char lsA[8192];                  // stage1 A: 64 rows x 128B
  __shared__ char lsW[EPITCH*256];            // 36KB: stage1 B / stage2 A / epilogue
  __shared__ char Ul[32768];                  // U: 64 x 256 bf16, chunk-swizzled

  int nwg = gridDim.x, bid = blockIdx.x;
  int wgid = (bid & 7)*(nwg >> 3) + (bid >> 3);   // grid 2048, %8==0
  size_t bc0 = (size_t)wgid * 64;
  int b = (int)(bc0 >> 9), c0 = (int)(bc0 & 511);

  const int tid = threadIdx.x;
  const int w = tid >> 6, l = tid & 63;
  const int la = l & 15, lg = l >> 4;

  f32x4 acc[4][4];
  #pragma unroll
  for (int i = 0; i < 4; ++i)
    #pragma unroll
    for (int j = 0; j < 4; ++j) acc[i][j] = (f32x4){0.f,0.f,0.f,0.f};

  // ===== stage 1: U = gelu(ht-tile @ w1a + b1a)   (m=64 bc, n=256 p1, k=256)
  for (int kt = 0; kt < 4; ++kt){
    int kb = kt << 6;
    #pragma unroll
    for (int i = 0; i < 2; ++i){
      int q = (i << 8) + tid;
      int row = q >> 3, sc = q & 7, cc = sc ^ (row & 7);
      gl2lds16(ht + (bc0 + row)*256 + kb + (cc << 3), lsA + q*16);
    }
    #pragma unroll
    for (int i = 0; i < 8; ++i){
      int q = (i << 8) + tid;
      int row = q >> 3, sc = q & 7, cc = sc ^ (row & 7);
      gl2lds16(w1aT + (size_t)row*256 + kb + (cc << 3), lsW + q*16);
    }
    __syncthreads();
    #pragma unroll
    for (int ks = 0; ks < 2; ++ks){
      int c = (ks << 2) + lg;
      bf16x8 af[4], bfr[4];
      #pragma unroll
      for (int mi = 0; mi < 4; ++mi){
        int rr = (mi << 4) + la;                       // bc-row (all waves share)
        af[mi] = *(const bf16x8*)(lsA + ((rr << 3) + (c ^ (rr & 7)))*16);
      }
      #pragma unroll
      for (int ni = 0; ni < 4; ++ni){
        int rn = (w << 6) + (ni << 4) + la;            // p1-row, wave n-split
        bfr[ni] = *(const bf16x8*)(lsW + ((rn << 3) + (c ^ (rn & 7)))*16);
      }
      #pragma unroll
      for (int mi = 0; mi < 4; ++mi)
        #pragma unroll
        for (int ni = 0; ni < 4; ++ni)
          acc[mi][ni] = __builtin_amdgcn_mfma_f32_16x16x32_bf16(af[mi], bfr[ni], acc[mi][ni], 0, 0, 0);
    }
    __syncthreads();
  }
  // U-write: bias(p1) + gelu, chunk-swizzled rows of 512B (32 chunks)
  #pragma unroll
  for (int ni = 0; ni < 4; ++ni){
    int p1 = (w << 6) + (ni << 4) + la;
    float bv = b1a[p1];
    int ckW = p1 >> 3, cw = p1 & 7;
    #pragma unroll
    for (int mi = 0; mi < 4; ++mi){
      #pragma unroll
      for (int rg = 0; rg < 4; ++rg){
        int bcr = (mi << 4) + (lg << 2) + rg;
        float v = gelu_f(acc[mi][ni][rg] + bv);
        *(unsigned short*)(Ul + (size_t)bcr*512 + (((ckW ^ (bcr & 7)) << 4) + (cw << 1))) = f2bf(v);
        acc[mi][ni][rg] = 0.0f;
      }
    }
  }
  __syncthreads();

  // ===== stage 2: t-tile = wt1b @ U^T + b1b   (m=256 p, n=64 bc, k=256 p1)
  for (int kt2 = 0; kt2 < 4; ++kt2){
    int kb = kt2 << 6;
    #pragma unroll
    for (int i = 0; i < 8; ++i){
      int q = (i << 8) + tid;
      int row = q >> 3, sc = q & 7, cc = sc ^ (row & 7);
      gl2lds16(w1bT + (size_t)row*256 + kb + (cc << 3), lsW + q*16);
    }
    __syncthreads();
    #pragma unroll
    for (int ks = 0; ks < 2; ++ks){
      int cch = (ks << 2) + lg;                        // chunk within kt2
      int cki = (kt2 << 3) + cch;                      // global chunk 0..31
      bf16x8 af[4], bfr[4];
      #pragma unroll
      for (int mi = 0; mi < 4; ++mi){
        int rp = (w << 6) + (mi << 4) + la;            // p-row, wave m-split
        af[mi] = *(const bf16x8*)(lsW + ((rp << 3) + (cch ^ (rp & 7)))*16);
      }
      #pragma unroll
      for (int ni = 0; ni < 4; ++ni){
        int rbc = (ni << 4) + la;                      // bc-row 0..63
        bfr[ni] = *(const bf16x8*)(Ul + (((size_t)rbc << 5) + (cki ^ (rbc & 7)))*16);
      }
      #pragma unroll
      for (int mi = 0; mi < 4; ++mi)
        #pragma unroll
        for (int ni = 0; ni < 4; ++ni)
          acc[mi][ni] = __builtin_amdgcn_mfma_f32_16x16x32_bf16(af[mi], bfr[ni], acc[mi][ni], 0, 0, 0);
    }
    __syncthreads();
  }

  // ===== epilogue: bias(p) per-row, stage via lsW (pitch 144), coalesced store
  #pragma unroll
  for (int mi = 0; mi < 4; ++mi){
    int rb = (w << 6) + (mi << 4) + (lg << 2);
    float4 bq = *(const float4*)(b1b + rb);
    #pragma unroll
    for (int ni = 0; ni < 4; ++ni){
      int col = (ni << 4) + la;
      #pragma unroll
      for (int rg = 0; rg < 4; ++rg){
        float v = acc[mi][ni][rg] + ((const float*)&bq)[rg];
        *(unsigned short*)(lsW + (rb + rg)*EPITCH + col*2) = f2bf(v);
      }
    }
  }
  __syncthreads();
  #pragma unroll
  for (int i = 0; i < 8; ++i){
    int q = (i << 8) + tid;
    int r = q >> 3, ck = q & 7;
    u16x8 val = *(const u16x8*)(lsW + r*EPITCH + ck*16);
    *(u16x8*)(t + ((size_t)b << 17) + (size_t)r*512 + c0 + (ck << 3)) = val;
  }
}

// ---- m97-style 128x128 GEMM (channel mixing), C[m][n] = epi(A·BT^T + bias)
// MODE 0: outb = bf16(gelu(v))   MODE 2: outf = f32(v) + f32(res[m][n])
// EPITCH=144 epilogue keeps LDS at 36,864 B -> 4 blocks/CU (was 45,056 -> 2-3).
template<int N, int KT, int MODE>
__global__ __launch_bounds__(256, 4) void k_gemm(
    const unsigned short* __restrict__ A,
    const unsigned short* __restrict__ BT,
    const float* __restrict__ bias,
    unsigned short* __restrict__ outb,
    float* __restrict__ outf,
    const unsigned short* __restrict__ res)
{
  constexpr int K = KT*64;
  constexpr int nTn = N/128;
  constexpr int EPITCH = 144;
  constexpr int EREG   = 64*EPITCH;           // 9216 B per wave region
  __shared__ char lds[4*EREG];                // 36,864 B; k-loop uses first 32,768
  char* lsA = lds;
  char* lsB = lds + 16384;

  int nwg = gridDim.x, bid = blockIdx.x;
  int wgid = ((nwg & 7) == 0) ? ((bid & 7)*(nwg >> 3) + (bid >> 3)) : bid;
  int tm = wgid / nTn, tn = wgid % nTn;
  size_t m0 = (size_t)tm * 128;
  int n0 = tn * 128;

  const int tid = threadIdx.x;
  const int w = tid >> 6, l = tid & 63;
  const int wm = w >> 1, wn = w & 1;
  const int la = l & 15, lg = l >> 4;

  f32x4 acc[4][4];
  #pragma unroll
  for (int i = 0; i < 4; ++i)
    #pragma unroll
    for (int j = 0; j < 4; ++j) acc[i][j] = (f32x4){0.f,0.f,0.f,0.f};

  for (int kt = 0; kt < KT; ++kt){
    int kb = kt << 6;
    #pragma unroll
    for (int i = 0; i < 4; ++i){
      int q = (i << 8) + tid;
      int row = q >> 3, sc = q & 7;
      int cc = sc ^ (row & 7);
      gl2lds16(A  + (m0 + row)*K + kb + (cc << 3), lsA + q*16);
      gl2lds16(BT + (size_t)(n0 + row)*K + kb + (cc << 3), lsB + q*16);
    }
    __syncthreads();
    #pragma unroll
    for (int ks = 0; ks < 2; ++ks){
      int c = (ks << 2) + lg;
      bf16x8 af[4], bfr[4];
      #pragma unroll
      for (int mi = 0; mi < 4; ++mi){
        int rr = (wm << 6) + (mi << 4) + la;
        af[mi] = *(const bf16x8*)(lsA + ((rr << 3) + (c ^ (rr & 7)))*16);
      }
      #pragma unroll
      for (int ni = 0; ni < 4; ++ni){
        int rn = (wn << 6) + (ni << 4) + la;
        bfr[ni] = *(const bf16x8*)(lsB + ((rn << 3) + (c ^ (rn & 7)))*16);
      }
      #pragma unroll
      for (int mi = 0; mi < 4; ++mi)
        #pragma unroll
        for (int ni = 0; ni < 4; ++ni)
          acc[mi][ni] = __builtin_amdgcn_mfma_f32_16x16x32_bf16(af[mi], bfr[ni], acc[mi][ni], 0, 0, 0);
    }
    __syncthreads();
  }

  char* ep = lds + w*EREG;
  #pragma unroll
  for (int ni = 0; ni < 4; ++ni){
    int colw = (ni << 4) + la;
    float bv = bias[n0 + (wn << 6) + colw];
    #pragma unroll
    for (int mi = 0; mi < 4; ++mi){
      #pragma unroll
      for (int rg = 0; rg < 4; ++rg){
        float v = acc[mi][ni][rg] + bv;
        if (MODE == 0) v = gelu_f(v);
        int r = (mi << 4) + (lg << 2) + rg;
        *(unsigned short*)(ep + r*EPITCH + colw*2) = f2bf(v);
      }
    }
  }
  __syncthreads();

  #pragma unroll
  for (int i = 0; i < 8; ++i){
    int q = (i << 8) + tid;
    int r = q >> 4, ck = q & 15;
    int wreg = ((r >> 6) << 1) | (ck >> 3);
    u16x8 val = *(const u16x8*)(lds + wreg*EREG + (r & 63)*EPITCH + (ck & 7)*16);
    size_t go = (m0 + r)*N + n0 + (ck << 3);
    if (MODE != 2){
      *(u16x8*)(outb + go) = val;
    } else {
      u16x8 rv = *(const u16x8*)(res + go);
      float4 o0, o1;
      o0.x = bf2f(val[0]) + bf2f(rv[0]);
      o0.y = bf2f(val[1]) + bf2f(rv[1]);
      o0.z = bf2f(val[2]) + bf2f(rv[2]);
      o0.w = bf2f(val[3]) + bf2f(rv[3]);
      o1.x = bf2f(val[4]) + bf2f(rv[4]);
      o1.y = bf2f(val[5]) + bf2f(rv[5]);
      o1.z = bf2f(val[6]) + bf2f(rv[6]);
      o1.w = bf2f(val[7]) + bf2f(rv[7]);
      *(float4*)(outf + go)     = o0;
      *(float4*)(outf + go + 4) = o1;
    }
  }
}

extern "C" void kernel_launch(void* const* d_in, const int* in_sizes, int n_in,
                              void* d_out, int out_size, void* d_ws, size_t ws_size,
                              hipStream_t stream) {
  const float* x   = (const float*)d_in[0];
  const float* lng = (const float*)d_in[1];
  const float* lnb = (const float*)d_in[2];
  const float* w1a = (const float*)d_in[3];
  const float* b1a = (const float*)d_in[4];
  const float* w1b = (const float*)d_in[5];
  const float* b1b = (const float*)d_in[6];
  const float* w2a = (const float*)d_in[7];
  const float* b2a = (const float*)d_in[8];
  const float* w2b = (const float*)d_in[9];
  const float* b2b = (const float*)d_in[10];
  float* out = (float*)d_out;
  char* ws = (char*)d_ws;
  unsigned short* bufA = (unsigned short*)ws;                         // 64 MiB
  unsigned short* bufB = (unsigned short*)(ws + (size_t)(64u << 20)); // 64 MiB
  unsigned short* wt1a = (unsigned short*)(ws + (size_t)(128u << 20));
  unsigned short* wt1b = wt1a + 256*256;
  unsigned short* wt2a = wt1b + 256*256;
  unsigned short* wt2b = wt2a + 512*512;

  k_wtt<<<160, 256, 0, stream>>>(w1a, w1b, w2a, w2b, wt1a, wt1b, wt2a, wt2b);

  // token mixing: LN1+transpose, then fused (gelu GEMM + GEMM) pair
  k_ln1x<<<2048, 512, 0, stream>>>(x, lng, lnb, bufA);                      // ht
  k_tok<<<2048, 256, 0, stream>>>(bufA, wt1a, wt1b, b1a, b1b, bufB);        // t_nat [b][p][c]

  // residual (from x, f32) + LN2
  k_tl2s<<<16384, 256, 0, stream>>>(bufB, x, lng, lnb, bufA);               // h2

  // channel mixing
  k_gemm<512, 8, 0><<<2048, 256, 0, stream>>>(bufA, wt2a, b2a, bufB, nullptr, nullptr); // u2
  k_gemm<512, 8, 2><<<2048, 256, 0, stream>>>(bufB, wt2b, b2b, nullptr, out, bufA);     // out
}

// Round 16
// 266.775 us; speedup vs baseline: 1.1270x; 1.1270x over previous
//
#include <hip/hip_runtime.h>
#include <hip/hip_bf16.h>
#include <math.h>

typedef __bf16 bf16x8 __attribute__((ext_vector_type(8)));
typedef float f32x4 __attribute__((ext_vector_type(4)));
typedef unsigned short u16x8 __attribute__((ext_vector_type(8)));

#define DEV __device__ __forceinline__

DEV unsigned short f2bf(float f){ __hip_bfloat16 h=__float2bfloat16(f); unsigned short u; __builtin_memcpy(&u,&h,2); return u; }
DEV float bf2f(unsigned short u){ __hip_bfloat16 h; __builtin_memcpy(&h,&u,2); return __bfloat162float(h); }

// tanh-form GELU: exp is HW (v_exp_f32), rcp is HW.
DEV float gelu_f(float v){
  float u = v*(0.7978845608f + 0.0356774081f*v*v);
  float e = __expf(2.0f*u);
  float t = 1.0f - 2.0f*__builtin_amdgcn_rcpf(e + 1.0f);
  return 0.5f*v*(1.0f + t);
}

DEV void gl2lds16(const void* g, void* l){
  __builtin_amdgcn_global_load_lds((const __attribute__((address_space(1))) void*)g,
                                   (__attribute__((address_space(3))) void*)l, 16, 0, 0);
}

// ---- tiled weight transpose: WT[n][k] (bf16) = W[k][n] (f32), 64x64 tiles.
__global__ __launch_bounds__(256) void k_wtt(const float* __restrict__ w1a,
                                             const float* __restrict__ w1b,
                                             const float* __restrict__ w2a,
                                             const float* __restrict__ w2b,
                                             unsigned short* __restrict__ o1a,
                                             unsigned short* __restrict__ o1b,
                                             unsigned short* __restrict__ o2a,
                                             unsigned short* __restrict__ o2b){
  __shared__ float tl[64][65];
  int bid = blockIdx.x;
  const float* W; unsigned short* O; int NN, tile_id;
  if (bid < 16)      { W = w1a; O = o1a; NN = 256; tile_id = bid; }
  else if (bid < 32) { W = w1b; O = o1b; NN = 256; tile_id = bid - 16; }
  else if (bid < 96) { W = w2a; O = o2a; NN = 512; tile_id = bid - 32; }
  else               { W = w2b; O = o2b; NN = 512; tile_id = bid - 96; }
  int tpr = NN >> 6;
  int tr = tile_id / tpr, tc = tile_id % tpr;
  int tid = threadIdx.x;
  int r = tid >> 2, cseg = (tid & 3) << 4;
  #pragma unroll
  for (int j = 0; j < 4; ++j){
    float4 v = *(const float4*)(W + (size_t)(tr*64 + r)*NN + tc*64 + cseg + j*4);
    tl[r][cseg + j*4 + 0] = v.x;
    tl[r][cseg + j*4 + 1] = v.y;
    tl[r][cseg + j*4 + 2] = v.z;
    tl[r][cseg + j*4 + 3] = v.w;
  }
  __syncthreads();
  int rn = tid >> 2, kseg = (tid & 3) << 4;
  #pragma unroll
  for (int h = 0; h < 2; ++h){
    u16x8 o;
    #pragma unroll
    for (int j = 0; j < 8; ++j) o[j] = f2bf(tl[kseg + h*8 + j][rn]);
    *(u16x8*)(O + (size_t)(tc*64 + rn)*NN + tr*64 + kseg + h*8) = o;
  }
}

// ---- LN1 + transpose: x[b][p][c] f32 -> ht[b][c][p] bf16 (layernormed)
__global__ __launch_bounds__(512) void k_ln1x(const float* __restrict__ x,
                                              const float* __restrict__ g,
                                              const float* __restrict__ be,
                                              unsigned short* __restrict__ ht){
  __shared__ unsigned short tile[32][512];
  int blk = blockIdx.x;
  int b = blk >> 3, p0 = (blk & 7) << 5;
  int tid = threadIdx.x, w = tid >> 6, l = tid & 63;
  float4 gv0 = *(const float4*)(g  + l*8);
  float4 gv1 = *(const float4*)(g  + l*8 + 4);
  float4 bv0 = *(const float4*)(be + l*8);
  float4 bv1 = *(const float4*)(be + l*8 + 4);
  const float* xbase = x + (((size_t)b << 8) + p0) * 512;
  #pragma unroll
  for (int i = 0; i < 4; ++i){
    int pl = (i << 3) + w;
    const float* row = xbase + (size_t)pl*512 + l*8;
    float4 v0 = *(const float4*)row;
    float4 v1 = *(const float4*)(row + 4);
    float s  = v0.x+v0.y+v0.z+v0.w + v1.x+v1.y+v1.z+v1.w;
    float s2 = v0.x*v0.x+v0.y*v0.y+v0.z*v0.z+v0.w*v0.w
             + v1.x*v1.x+v1.y*v1.y+v1.z*v1.z+v1.w*v1.w;
    #pragma unroll
    for (int off = 32; off; off >>= 1){ s += __shfl_xor(s, off); s2 += __shfl_xor(s2, off); }
    float mu = s * (1.0f/512.0f);
    float rs = rsqrtf(s2*(1.0f/512.0f) - mu*mu + 1e-6f);
    u16x8 o;
    o[0]=f2bf((v0.x-mu)*rs*gv0.x+bv0.x);
    o[1]=f2bf((v0.y-mu)*rs*gv0.y+bv0.y);
    o[2]=f2bf((v0.z-mu)*rs*gv0.z+bv0.z);
    o[3]=f2bf((v0.w-mu)*rs*gv0.w+bv0.w);
    o[4]=f2bf((v1.x-mu)*rs*gv1.x+bv1.x);
    o[5]=f2bf((v1.y-mu)*rs*gv1.y+bv1.y);
    o[6]=f2bf((v1.z-mu)*rs*gv1.z+bv1.z);
    o[7]=f2bf((v1.w-mu)*rs*gv1.w+bv1.w);
    *(u16x8*)(&tile[pl][(l ^ ((pl >> 3) << 1)) << 3]) = o;   // swizzled chunk
  }
  __syncthreads();
  unsigned short* hb = ht + ((size_t)b << 17);   // b * 512 * 256
  #pragma unroll
  for (int it = 0; it < 4; ++it){
    int c = (it << 7) + (tid >> 2);
    int q = tid & 3, pch = q << 3;
    int cs = c ^ (q << 4);
    u16x8 o;
    #pragma unroll
    for (int j = 0; j < 8; ++j) o[j] = tile[pch + j][cs];
    *(u16x8*)(hb + (size_t)c*256 + p0 + pch) = o;
  }
}

// ---- streaming residual + LN2, one row per wave; residual read from x (f32):
__global__ __launch_bounds__(256) void k_tl2s(const unsigned short* __restrict__ t,
                                              const float* __restrict__ x,
                                              const float* __restrict__ g,
                                              const float* __restrict__ be,
                                              unsigned short* __restrict__ h2){
  int tid = threadIdx.x, w = tid >> 6, l = tid & 63;
  float4 gv0 = *(const float4*)(g  + l*8);
  float4 gv1 = *(const float4*)(g  + l*8 + 4);
  float4 bv0 = *(const float4*)(be + l*8);
  float4 bv1 = *(const float4*)(be + l*8 + 4);
  int r = blockIdx.x*4 + w;
  size_t off = (size_t)r*512 + l*8;
  u16x8 tv = *(const u16x8*)(t + off);
  float4 x0 = *(const float4*)(x + off);
  float4 x1 = *(const float4*)(x + off + 4);
  float v[8];
  v[0] = bf2f(tv[0]) + x0.x;
  v[1] = bf2f(tv[1]) + x0.y;
  v[2] = bf2f(tv[2]) + x0.z;
  v[3] = bf2f(tv[3]) + x0.w;
  v[4] = bf2f(tv[4]) + x1.x;
  v[5] = bf2f(tv[5]) + x1.y;
  v[6] = bf2f(tv[6]) + x1.z;
  v[7] = bf2f(tv[7]) + x1.w;
  float s = 0.f, s2 = 0.f;
  #pragma unroll
  for (int j = 0; j < 8; ++j){ s += v[j]; s2 += v[j]*v[j]; }
  #pragma unroll
  for (int o2i = 32; o2i; o2i >>= 1){ s += __shfl_xor(s, o2i); s2 += __shfl_xor(s2, o2i); }
  float mu = s * (1.0f/512.0f);
  float rs = rsqrtf(s2*(1.0f/512.0f) - mu*mu + 1e-6f);
  u16x8 o;
  o[0]=f2bf((v[0]-mu)*rs*gv0.x+bv0.x);
  o[1]=f2bf((v[1]-mu)*rs*gv0.y+bv0.y);
  o[2]=f2bf((v[2]-mu)*rs*gv0.z+bv0.z);
  o[3]=f2bf((v[3]-mu)*rs*gv0.w+bv0.w);
  o[4]=f2bf((v[4]-mu)*rs*gv1.x+bv1.x);
  o[5]=f2bf((v[5]-mu)*rs*gv1.y+bv1.y);
  o[6]=f2bf((v[6]-mu)*rs*gv1.z+bv1.z);
  o[7]=f2bf((v[7]-mu)*rs*gv1.w+bv1.w);
  *(u16x8*)(h2 + off) = o;
}

// ---- fused token MLP (proven round-13 form):
__global__ __launch_bounds__(256, 2) void k_tok(
    const unsigned short* __restrict__ ht,    // [131072][256]
    const unsigned short* __restrict__ w1aT,  // [p1][p'] 256x256
    const unsigned short* __restrict__ w1bT,  // [p][p1]  256x256
    const float* __restrict__ b1a,
    const float* __restrict__ b1b,
    unsigned short* __restrict__ t)           // [256][256][512]
{
  constexpr int EPITCH = 144;
  __shared__ char lsA[8192];
  __shared__ char lsW[EPITCH*256];
  __shared__ char Ul[32768];

  int nwg = gridDim.x, bid = blockIdx.x;
  int wgid = (bid & 7)*(nwg >> 3) + (bid >> 3);
  size_t bc0 = (size_t)wgid * 64;
  int b = (int)(bc0 >> 9), c0 = (int)(bc0 & 511);

  const int tid = threadIdx.x;
  const int w = tid >> 6, l = tid & 63;
  const int la = l & 15, lg = l >> 4;

  f32x4 acc[4][4];
  #pragma unroll
  for (int i = 0; i < 4; ++i)
    #pragma unroll
    for (int j = 0; j < 4; ++j) acc[i][j] = (f32x4){0.f,0.f,0.f,0.f};

  // stage 1: U = gelu(ht-tile @ w1a + b1a)
  for (int kt = 0; kt < 4; ++kt){
    int kb = kt << 6;
    #pragma unroll
    for (int i = 0; i < 2; ++i){
      int q = (i << 8) + tid;
      int row = q >> 3, sc = q & 7, cc = sc ^ (row & 7);
      gl2lds16(ht + (bc0 + row)*256 + kb + (cc << 3), lsA + q*16);
    }
    #pragma unroll
    for (int i = 0; i < 8; ++i){
      int q = (i << 8) + tid;
      int row = q >> 3, sc = q & 7, cc = sc ^ (row & 7);
      gl2lds16(w1aT + (size_t)row*256 + kb + (cc << 3), lsW + q*16);
    }
    __syncthreads();
    #pragma unroll
    for (int ks = 0; ks < 2; ++ks){
      int c = (ks << 2) + lg;
      bf16x8 af[4], bfr[4];
      #pragma unroll
      for (int mi = 0; mi < 4; ++mi){
        int rr = (mi << 4) + la;
        af[mi] = *(const bf16x8*)(lsA + ((rr << 3) + (c ^ (rr & 7)))*16);
      }
      #pragma unroll
      for (int ni = 0; ni < 4; ++ni){
        int rn = (w << 6) + (ni << 4) + la;
        bfr[ni] = *(const bf16x8*)(lsW + ((rn << 3) + (c ^ (rn & 7)))*16);
      }
      #pragma unroll
      for (int mi = 0; mi < 4; ++mi)
        #pragma unroll
        for (int ni = 0; ni < 4; ++ni)
          acc[mi][ni] = __builtin_amdgcn_mfma_f32_16x16x32_bf16(af[mi], bfr[ni], acc[mi][ni], 0, 0, 0);
    }
    __syncthreads();
  }
  #pragma unroll
  for (int ni = 0; ni < 4; ++ni){
    int p1 = (w << 6) + (ni << 4) + la;
    float bv = b1a[p1];
    int ckW = p1 >> 3, cw = p1 & 7;
    #pragma unroll
    for (int mi = 0; mi < 4; ++mi){
      #pragma unroll
      for (int rg = 0; rg < 4; ++rg){
        int bcr = (mi << 4) + (lg << 2) + rg;
        float v = gelu_f(acc[mi][ni][rg] + bv);
        *(unsigned short*)(Ul + (size_t)bcr*512 + (((ckW ^ (bcr & 7)) << 4) + (cw << 1))) = f2bf(v);
        acc[mi][ni][rg] = 0.0f;
      }
    }
  }
  __syncthreads();

  // stage 2: t-tile = wt1b @ U^T + b1b
  for (int kt2 = 0; kt2 < 4; ++kt2){
    int kb = kt2 << 6;
    #pragma unroll
    for (int i = 0; i < 8; ++i){
      int q = (i << 8) + tid;
      int row = q >> 3, sc = q & 7, cc = sc ^ (row & 7);
      gl2lds16(w1bT + (size_t)row*256 + kb + (cc << 3), lsW + q*16);
    }
    __syncthreads();
    #pragma unroll
    for (int ks = 0; ks < 2; ++ks){
      int cch = (ks << 2) + lg;
      int cki = (kt2 << 3) + cch;
      bf16x8 af[4], bfr[4];
      #pragma unroll
      for (int mi = 0; mi < 4; ++mi){
        int rp = (w << 6) + (mi << 4) + la;
        af[mi] = *(const bf16x8*)(lsW + ((rp << 3) + (cch ^ (rp & 7)))*16);
      }
      #pragma unroll
      for (int ni = 0; ni < 4; ++ni){
        int rbc = (ni << 4) + la;
        bfr[ni] = *(const bf16x8*)(Ul + (((size_t)rbc << 5) + (cki ^ (rbc & 7)))*16);
      }
      #pragma unroll
      for (int mi = 0; mi < 4; ++mi)
        #pragma unroll
        for (int ni = 0; ni < 4; ++ni)
          acc[mi][ni] = __builtin_amdgcn_mfma_f32_16x16x32_bf16(af[mi], bfr[ni], acc[mi][ni], 0, 0, 0);
    }
    __syncthreads();
  }

  #pragma unroll
  for (int mi = 0; mi < 4; ++mi){
    int rb = (w << 6) + (mi << 4) + (lg << 2);
    float4 bq = *(const float4*)(b1b + rb);
    #pragma unroll
    for (int ni = 0; ni < 4; ++ni){
      int col = (ni << 4) + la;
      #pragma unroll
      for (int rg = 0; rg < 4; ++rg){
        float v = acc[mi][ni][rg] + ((const float*)&bq)[rg];
        *(unsigned short*)(lsW + (rb + rg)*EPITCH + col*2) = f2bf(v);
      }
    }
  }
  __syncthreads();
  #pragma unroll
  for (int i = 0; i < 8; ++i){
    int q = (i << 8) + tid;
    int r = q >> 3, ck = q & 7;
    u16x8 val = *(const u16x8*)(lsW + r*EPITCH + ck*16);
    *(u16x8*)(t + ((size_t)b << 17) + (size_t)r*512 + c0 + (ck << 3)) = val;
  }
}

// ---- 256x128-tile GEMM (channel mixing), C[m][n] = epi(A·BT^T + bias)
// Per wave 128x64 output (acc 8x4) -> 2x MFMA per barrier vs 128-tile.
// Epilogue reuses the 48KB staging LDS in two 64-row passes (EPITCH 144).
// MODE 0: outb = bf16(gelu(v))   MODE 2: outf = f32(v) + f32(res[m][n])
template<int N, int KT, int MODE>
__global__ __launch_bounds__(256, 2) void k_gemm(
    const unsigned short* __restrict__ A,
    const unsigned short* __restrict__ BT,
    const float* __restrict__ bias,
    unsigned short* __restrict__ outb,
    float* __restrict__ outf,
    const unsigned short* __restrict__ res)
{
  constexpr int K = KT*64;
  constexpr int nTn = N/128;
  constexpr int EPITCH = 144;
  constexpr int EREG   = 64*EPITCH;           // 9216 B per wave region per pass
  __shared__ char lds[49152];                 // A 32KB + B 16KB; epilogue reuses
  char* lsA = lds;
  char* lsB = lds + 32768;

  int nwg = gridDim.x, bid = blockIdx.x;
  int wgid = ((nwg & 7) == 0) ? ((bid & 7)*(nwg >> 3) + (bid >> 3)) : bid;
  int tm = wgid / nTn, tn = wgid % nTn;
  size_t m0 = (size_t)tm * 256;
  int n0 = tn * 128;

  const int tid = threadIdx.x;
  const int w = tid >> 6, l = tid & 63;
  const int wm = w >> 1, wn = w & 1;
  const int la = l & 15, lg = l >> 4;

  f32x4 acc[8][4];
  #pragma unroll
  for (int i = 0; i < 8; ++i)
    #pragma unroll
    for (int j = 0; j < 4; ++j) acc[i][j] = (f32x4){0.f,0.f,0.f,0.f};

  for (int kt = 0; kt < KT; ++kt){
    int kb = kt << 6;
    #pragma unroll
    for (int i = 0; i < 8; ++i){              // A: 256 rows x 8 chunks
      int q = (i << 8) + tid;
      int row = q >> 3, sc = q & 7;
      int cc = sc ^ (row & 7);
      gl2lds16(A + (m0 + row)*K + kb + (cc << 3), lsA + q*16);
    }
    #pragma unroll
    for (int i = 0; i < 4; ++i){              // B: 128 rows x 8 chunks
      int q = (i << 8) + tid;
      int row = q >> 3, sc = q & 7;
      int cc = sc ^ (row & 7);
      gl2lds16(BT + (size_t)(n0 + row)*K + kb + (cc << 3), lsB + q*16);
    }
    __syncthreads();
    #pragma unroll
    for (int ks = 0; ks < 2; ++ks){
      int c = (ks << 2) + lg;
      bf16x8 af[8], bfr[4];
      #pragma unroll
      for (int mi = 0; mi < 8; ++mi){
        int rr = (wm << 7) + (mi << 4) + la;
        af[mi] = *(const bf16x8*)(lsA + ((rr << 3) + (c ^ (rr & 7)))*16);
      }
      #pragma unroll
      for (int ni = 0; ni < 4; ++ni){
        int rn = (wn << 6) + (ni << 4) + la;
        bfr[ni] = *(const bf16x8*)(lsB + ((rn << 3) + (c ^ (rn & 7)))*16);
      }
      #pragma unroll
      for (int mi = 0; mi < 8; ++mi)
        #pragma unroll
        for (int ni = 0; ni < 4; ++ni)
          acc[mi][ni] = __builtin_amdgcn_mfma_f32_16x16x32_bf16(af[mi], bfr[ni], acc[mi][ni], 0, 0, 0);
    }
    __syncthreads();
  }

  // ---- epilogue: two 64-row passes through LDS (per-wave region 9216 B)
  #pragma unroll
  for (int p = 0; p < 2; ++p){
    char* ep = lds + w*EREG;
    #pragma unroll
    for (int ni = 0; ni < 4; ++ni){
      int colw = (ni << 4) + la;
      float bv = bias[n0 + (wn << 6) + colw];
      #pragma unroll
      for (int mi2 = 0; mi2 < 4; ++mi2){
        #pragma unroll
        for (int rg = 0; rg < 4; ++rg){
          float v = acc[p*4 + mi2][ni][rg] + bv;
          if (MODE == 0) v = gelu_f(v);
          int r = (mi2 << 4) + (lg << 2) + rg;
          *(unsigned short*)(ep + r*EPITCH + colw*2) = f2bf(v);
        }
      }
    }
    __syncthreads();
    #pragma unroll
    for (int i = 0; i < 8; ++i){
      int q = (i << 8) + tid;
      int r = q >> 4, ck = q & 15;
      int wreg = ((r >> 6) << 1) | (ck >> 3);
      u16x8 val = *(const u16x8*)(lds + wreg*EREG + (r & 63)*EPITCH + (ck & 7)*16);
      int grow = ((r >> 6) << 7) + (p << 6) + (r & 63);
      size_t go = (m0 + grow)*N + n0 + (ck << 3);
      if (MODE != 2){
        *(u16x8*)(outb + go) = val;
      } else {
        u16x8 rv = *(const u16x8*)(res + go);
        float4 o0, o1;
        o0.x = bf2f(val[0]) + bf2f(rv[0]);
        o0.y = bf2f(val[1]) + bf2f(rv[1]);
        o0.z = bf2f(val[2]) + bf2f(rv[2]);
        o0.w = bf2f(val[3]) + bf2f(rv[3]);
        o1.x = bf2f(val[4]) + bf2f(rv[4]);
        o1.y = bf2f(val[5]) + bf2f(rv[5]);
        o1.z = bf2f(val[6]) + bf2f(rv[6]);
        o1.w = bf2f(val[7]) + bf2f(rv[7]);
        *(float4*)(outf + go)     = o0;
        *(float4*)(outf + go + 4) = o1;
      }
    }
    __syncthreads();
  }
}

extern "C" void kernel_launch(void* const* d_in, const int* in_sizes, int n_in,
                              void* d_out, int out_size, void* d_ws, size_t ws_size,
                              hipStream_t stream) {
  const float* x   = (const float*)d_in[0];
  const float* lng = (const float*)d_in[1];
  const float* lnb = (const float*)d_in[2];
  const float* w1a = (const float*)d_in[3];
  const float* b1a = (const float*)d_in[4];
  const float* w1b = (const float*)d_in[5];
  const float* b1b = (const float*)d_in[6];
  const float* w2a = (const float*)d_in[7];
  const float* b2a = (const float*)d_in[8];
  const float* w2b = (const float*)d_in[9];
  const float* b2b = (const float*)d_in[10];
  float* out = (float*)d_out;
  char* ws = (char*)d_ws;
  unsigned short* bufA = (unsigned short*)ws;                         // 64 MiB
  unsigned short* bufB = (unsigned short*)(ws + (size_t)(64u << 20)); // 64 MiB
  unsigned short* wt1a = (unsigned short*)(ws + (size_t)(128u << 20));
  unsigned short* wt1b = wt1a + 256*256;
  unsigned short* wt2a = wt1b + 256*256;
  unsigned short* wt2b = wt2a + 512*512;

  k_wtt<<<160, 256, 0, stream>>>(w1a, w1b, w2a, w2b, wt1a, wt1b, wt2a, wt2b);

  // token mixing: LN1+transpose, then fused (gelu GEMM + GEMM) pair
  k_ln1x<<<2048, 512, 0, stream>>>(x, lng, lnb, bufA);                      // ht
  k_tok<<<2048, 256, 0, stream>>>(bufA, wt1a, wt1b, b1a, b1b, bufB);        // t_nat [b][p][c]

  // residual (from x, f32) + LN2
  k_tl2s<<<16384, 256, 0, stream>>>(bufB, x, lng, lnb, bufA);               // h2

  // channel mixing (256x128-tile GEMMs, 1024 blocks)
  k_gemm<512, 8, 0><<<1024, 256, 0, stream>>>(bufA, wt2a, b2a, bufB, nullptr, nullptr); // u2
  k_gemm<512, 8, 2><<<1024, 256, 0, stream>>>(bufB, wt2b, b2b, nullptr, out, bufA);     // out
}